// Round 4
// baseline (537.733 us; speedup 1.0000x reference)
//
#include <hip/hip_runtime.h>
#include <hip/hip_bf16.h>

// Problem constants
#define BS  32
#define N   1024
#define DIM 1024

typedef unsigned short u16;
typedef unsigned int   u32;

typedef __attribute__((ext_vector_type(8))) __bf16 bf16x8;
typedef __attribute__((ext_vector_type(4))) float  f32x4;

__device__ __forceinline__ u16 f2bf(float f) {
    u32 u = __builtin_bit_cast(u32, f);
    u = (u + 0x7FFF + ((u >> 16) & 1)) >> 16;   // RNE, finite inputs only
    return (u16)u;
}

// ---------------------------------------------------------------------------
// K1: convert x (and Wv) to bf16, fused with q = x.Wq+bq, k = x.Wk+bk.
__global__ void convert_qk(const float* __restrict__ x,
                           const float* __restrict__ Wq, const float* __restrict__ bq,
                           const float* __restrict__ Wk, const float* __restrict__ bk,
                           const float* __restrict__ Wv,
                           u16* __restrict__ xb, u16* __restrict__ Wvb,
                           float* __restrict__ qv, float* __restrict__ kv)
{
    int gw   = (blockIdx.x * 256 + threadIdx.x) >> 6;
    int lane = threadIdx.x & 63;
    bool isX = gw < BS * N;
    const float* src = isX ? (x + (size_t)gw * DIM) : (Wv + (size_t)(gw - BS * N) * DIM);
    u16*         dst = isX ? (xb + (size_t)gw * DIM) : (Wvb + (size_t)(gw - BS * N) * DIM);
    float qd = 0.f, kd = 0.f;
    #pragma unroll
    for (int i = 0; i < 4; ++i) {
        int e = i * 256 + lane * 4;
        float4 xv = *(const float4*)&src[e];
        uint2 p;
        p.x = (u32)f2bf(xv.x) | ((u32)f2bf(xv.y) << 16);
        p.y = (u32)f2bf(xv.z) | ((u32)f2bf(xv.w) << 16);
        *(uint2*)&dst[e] = p;
        if (isX) {
            float4 wq = *(const float4*)&Wq[e];
            float4 wk = *(const float4*)&Wk[e];
            qd += xv.x * wq.x + xv.y * wq.y + xv.z * wq.z + xv.w * wq.w;
            kd += xv.x * wk.x + xv.y * wk.y + xv.z * wk.z + xv.w * wk.w;
        }
    }
    if (isX) {
        #pragma unroll
        for (int off = 32; off; off >>= 1) {
            qd += __shfl_xor(qd, off);
            kd += __shfl_xor(kd, off);
        }
        if (lane == 0) { qv[gw] = qd + bq[0]; kv[gw] = kd + bk[0]; }
    }
}

// ---------------------------------------------------------------------------
// K2: Z row-sums only -> (q, invZ) pairs.
__global__ void qz_writer(const float* __restrict__ qv, const float* __restrict__ kvg,
                          float2* __restrict__ qzg)
{
    int blk = blockIdx.x;
    int b   = blk >> 6;
    int r0  = (blk & 63) * 16;
    __shared__ float ks[1024];
    int tid = threadIdx.x;
    #pragma unroll
    for (int i = 0; i < 4; ++i) ks[i * 256 + tid] = kvg[b * N + i * 256 + tid];
    int row = tid >> 4;
    int c16 = tid & 15;
    float qrow = qv[b * N + r0 + row];
    __syncthreads();
    float z = 0.f;
    #pragma unroll 4
    for (int s = 0; s < 16; ++s) {
        const float4 kk = *(const float4*)&ks[(c16 + s * 16) * 4];
        z += __expf(qrow * kk.x) + __expf(qrow * kk.y)
           + __expf(qrow * kk.z) + __expf(qrow * kk.w);
    }
    z += __shfl_xor(z, 1); z += __shfl_xor(z, 2);
    z += __shfl_xor(z, 4); z += __shfl_xor(z, 8);
    if (c16 == 0) qzg[b * N + r0 + row] = make_float2(qrow, 1.0f / z);
}

// ---------------------------------------------------------------------------
// K2b: 64x64 tiles of attention (fp32 output only; attT generated in gemm2f).
__global__ void att_tiles(const float2* __restrict__ qzg, const float* __restrict__ kvg,
                          float* __restrict__ att)
{
    int blk  = blockIdx.x;
    int b    = blk >> 8;
    int rest = blk & 255;
    int r0 = (rest >> 4) * 64;
    int c0 = (rest & 15) * 64;
    int tid = threadIdx.x;
    int tx = tid & 15, ty = tid >> 4;

    float q[4], iz[4];
    #pragma unroll
    for (int i = 0; i < 4; ++i) {
        float2 p = qzg[(size_t)b * N + r0 + tx * 4 + i];
        q[i] = p.x; iz[i] = p.y;
    }
    float kvj[4];
    #pragma unroll
    for (int j = 0; j < 4; ++j) kvj[j] = kvg[(size_t)b * N + c0 + ty * 4 + j];

    float* ab = att + (size_t)b * N * N;
    #pragma unroll
    for (int i = 0; i < 4; ++i) {
        float4 o;
        o.x = __expf(q[i] * kvj[0]) * iz[i];
        o.y = __expf(q[i] * kvj[1]) * iz[i];
        o.z = __expf(q[i] * kvj[2]) * iz[i];
        o.w = __expf(q[i] * kvj[3]) * iz[i];
        *(float4*)&ab[(size_t)(r0 + tx * 4 + i) * N + c0 + ty * 4] = o;
    }
}

// ===========================================================================
// 8-phase 256x256 GEMM (T2+T3+T4+T5), C[b] = A[b] (1024xK rm) @ B[b]^T (1024xK rm).
// (gemm1: A=Wvb shared, B=xb, bf16+bias out.) Unchanged from round 2 (verified).
// ===========================================================================

__device__ __forceinline__ void stage_half8(const u16* __restrict__ Aptr,
                                            const u16* __restrict__ Bptr,
                                            int m0b, int n0b, char* smem,
                                            int h, int w, int lane)
{
    if (h >= 64) return;
    int tile = h >> 2, id = h & 3;
    int db   = tile & 1;
    const u16* G = (id < 2) ? Bptr : Aptr;
    int opb   = (id < 2) ? 65536 : 0;
    int row0  = (id < 2) ? n0b : m0b;
    int halfb = (id & 1) * 16384;
    int kb    = tile * 128;                       // BK=64 -> 128 bytes
    int cb    = ((lane & 7) ^ (lane >> 3)) << 4;  // pre-swizzled source column
    #pragma unroll
    for (int i = 0; i < 2; ++i) {
        int lofs = opb + db * 32768 + halfb + (i * 8 + w) * 1024;  // wave-uniform
        int r    = (id & 1) * 128 + (i * 8 + w) * 8 + (lane >> 3);
        const char* src = (const char*)G + (size_t)(row0 + r) * 2048 + kb + cb;
        __builtin_amdgcn_global_load_lds(
            (const __attribute__((address_space(1))) u32*)src,
            (__attribute__((address_space(3))) u32*)(smem + lofs), 16, 0, 0);
    }
}

__global__ __launch_bounds__(512, 2) void gemm8p(
    const u16* __restrict__ A, size_t aBatch,
    const u16* __restrict__ B, size_t bBatch,
    u16* __restrict__ C, size_t cBatch,
    const float* __restrict__ bias)
{
    __shared__ char smem[131072];
    int bid = blockIdx.x;
    int lin = (bid & 7) * 64 + (bid >> 3);
    int b   = lin >> 4;
    int t16 = lin & 15;
    int m0b = (t16 >> 2) * 256, n0b = (t16 & 3) * 256;
    const u16* Aptr = A + aBatch * (size_t)b;
    const u16* Bptr = B + bBatch * (size_t)b;

    int tid  = threadIdx.x;
    int w    = tid >> 6, lane = tid & 63;
    int wm   = w >> 2, wn = w & 3;

    f32x4 acc[8][4] = {};
    bf16x8 aP[2][2], aQ[2][2], bF[4][2];

#define LDA_(dst, fi, ks) dst = *(const bf16x8*)(smem + jdb * 32768 + \
        (wm * 128 + (fi) * 16 + (lane & 15)) * 128 + \
        ((((ks) * 64) + ((lane >> 4) << 4)) ^ ((lane & 7) << 4)))
#define LDB_(dst, ni, ks) dst = *(const bf16x8*)(smem + 65536 + jdb * 32768 + \
        (wn * 64 + (ni) * 16 + (lane & 15)) * 128 + \
        ((((ks) * 64) + ((lane >> 4) << 4)) ^ ((lane & 7) << 4)))
#define MFMA_HALF(FI0, AR) do { \
        __builtin_amdgcn_s_setprio(1); \
        _Pragma("unroll") \
        for (int mi = 0; mi < 2; ++mi) \
            _Pragma("unroll") \
            for (int ni = 0; ni < 4; ++ni) \
                _Pragma("unroll") \
                for (int ks = 0; ks < 2; ++ks) \
                    acc[(FI0) + mi][ni] = __builtin_amdgcn_mfma_f32_16x16x32_bf16( \
                        AR[mi][ks], bF[ni][ks], acc[(FI0) + mi][ni], 0, 0, 0); \
        __builtin_amdgcn_s_setprio(0); \
    } while (0)

    #pragma unroll
    for (int h = 0; h < 7; ++h) stage_half8(Aptr, Bptr, m0b, n0b, smem, h, w, lane);
    asm volatile("s_waitcnt vmcnt(6)" ::: "memory");
    __builtin_amdgcn_s_barrier();
    __builtin_amdgcn_sched_barrier(0);

    #pragma unroll 1
    for (int j = 0; j < 16; ++j) {
        const int jdb = j & 1;
        LDA_(aP[0][0], 0, 0); LDA_(aP[0][1], 0, 1);
        LDA_(aP[1][0], 1, 0); LDA_(aP[1][1], 1, 1);
        LDA_(aQ[0][0], 2, 0); LDA_(aQ[0][1], 2, 1);
        LDA_(aQ[1][0], 3, 0); LDA_(aQ[1][1], 3, 1);
        LDB_(bF[0][0], 0, 0); LDB_(bF[0][1], 0, 1);
        LDB_(bF[1][0], 1, 0); LDB_(bF[1][1], 1, 1);
        LDB_(bF[2][0], 2, 0); LDB_(bF[2][1], 2, 1);
        LDB_(bF[3][0], 3, 0); LDB_(bF[3][1], 3, 1);
        stage_half8(Aptr, Bptr, m0b, n0b, smem, 7 + 4 * j, w, lane);
        __builtin_amdgcn_s_barrier();
        asm volatile("s_waitcnt lgkmcnt(0)" ::: "memory");
        MFMA_HALF(0, aP);
        __builtin_amdgcn_s_barrier();
        LDA_(aP[0][0], 4, 0); LDA_(aP[0][1], 4, 1);
        LDA_(aP[1][0], 5, 0); LDA_(aP[1][1], 5, 1);
        stage_half8(Aptr, Bptr, m0b, n0b, smem, 8 + 4 * j, w, lane);
        __builtin_amdgcn_s_barrier();
        asm volatile("s_waitcnt lgkmcnt(0)" ::: "memory");
        MFMA_HALF(2, aQ);
        __builtin_amdgcn_s_barrier();
        LDA_(aQ[0][0], 6, 0); LDA_(aQ[0][1], 6, 1);
        LDA_(aQ[1][0], 7, 0); LDA_(aQ[1][1], 7, 1);
        stage_half8(Aptr, Bptr, m0b, n0b, smem, 9 + 4 * j, w, lane);
        __builtin_amdgcn_s_barrier();
        asm volatile("s_waitcnt lgkmcnt(0)" ::: "memory");
        MFMA_HALF(4, aP);
        __builtin_amdgcn_s_barrier();
        stage_half8(Aptr, Bptr, m0b, n0b, smem, 10 + 4 * j, w, lane);
        __builtin_amdgcn_s_barrier();
        asm volatile("s_waitcnt lgkmcnt(0)" ::: "memory");
        MFMA_HALF(6, aQ);
        if (j < 14)       asm volatile("s_waitcnt vmcnt(6)" ::: "memory");
        else if (j == 14) asm volatile("s_waitcnt vmcnt(0)" ::: "memory");
        __builtin_amdgcn_s_barrier();
        __builtin_amdgcn_sched_barrier(0);
    }
#undef LDA_
#undef LDB_
#undef MFMA_HALF

    int r4 = (lane >> 4) * 4, cc = lane & 15;
    u16* Cb = C + cBatch * (size_t)b;
    #pragma unroll
    for (int fi = 0; fi < 8; ++fi)
        #pragma unroll
        for (int ni = 0; ni < 4; ++ni)
            #pragma unroll
            for (int rg = 0; rg < 4; ++rg) {
                int row = m0b + wm * 128 + fi * 16 + r4 + rg;
                int col = n0b + wn * 64 + ni * 16 + cc;
                Cb[(size_t)row * 1024 + col] = f2bf(acc[fi][ni][rg] + bias[row]);
            }
}

// ===========================================================================
// gemm2f: out[b] = vb[b] @ B^T with B[m][k] = exp(q_k*kv_m)*iz_k GENERATED
// into LDS in-kernel. FIX vs round 3: qz prologue gload source is PER-LANE
// (+lane*16) — round 3 passed a wave-uniform source so all lanes fetched the
// same 16 B and qzs was garbage (rule m104: per-lane src, uniform dest).
// GEN now uses f2bf RNE pack (bit-identical to the attT gload path).
// ===========================================================================

__device__ __forceinline__ void stageA2(const u16* __restrict__ Ap,
                                        int m0b, char* smem,
                                        int T, int hh, int w, int lane)
{
    int db = T & 1;
    int kb = T * 128;
    int cb = ((lane & 7) ^ (lane >> 3)) << 4;
    #pragma unroll
    for (int i = 0; i < 2; ++i) {
        int lofs = db * 32768 + hh * 16384 + (i * 8 + w) * 1024;
        int r    = hh * 128 + (i * 8 + w) * 8 + (lane >> 3);
        const char* src = (const char*)Ap + (size_t)(m0b + r) * 2048 + kb + cb;
        __builtin_amdgcn_global_load_lds(
            (const __attribute__((address_space(1))) u32*)src,
            (__attribute__((address_space(3))) u32*)(smem + lofs), 16, 0, 0);
    }
}

__global__ __launch_bounds__(512, 2) void gemm2f(
    const u16* __restrict__ A,          // vb: per-batch 1024x1024 bf16 rm
    const float2* __restrict__ qzg,     // per-batch N of (q, invZ)
    const float* __restrict__ kvg,      // per-batch N of k
    float* __restrict__ C)              // out: per-batch 1024x1024 fp32 rm
{
    __shared__ char smem[139264];       // A dbuf 64K | B dbuf 64K | qz 8K
    float2* qzs = (float2*)(smem + 131072);

    int bid = blockIdx.x;
    int lin = (bid & 7) * 64 + (bid >> 3);
    int b   = lin >> 4;
    int t16 = lin & 15;
    int m0b = (t16 >> 2) * 256, n0b = (t16 & 3) * 256;
    const u16* Aptr = A + (size_t)b * 1024 * 1024;

    int tid  = threadIdx.x;
    int w    = tid >> 6, lane = tid & 63;
    int wm   = w >> 2, wn = w & 3;

    // kv for the 4 rows this thread generates: r = h*128 + (i*8+w)*8 + (lane>>3)
    float kvr[4];
    #pragma unroll
    for (int h = 0; h < 2; ++h)
        #pragma unroll
        for (int i = 0; i < 2; ++i)
            kvr[h * 2 + i] = kvg[(size_t)b * N + n0b + h * 128 + (i * 8 + w) * 8 + (lane >> 3)];

    f32x4 acc[8][4] = {};
    bf16x8 aP[2][2], aQ[2][2], bF[4][2];

#define LDA_(dst, fi, ks) dst = *(const bf16x8*)(smem + jdb * 32768 + \
        (wm * 128 + (fi) * 16 + (lane & 15)) * 128 + \
        ((((ks) * 64) + ((lane >> 4) << 4)) ^ ((lane & 7) << 4)))
#define LDB_(dst, ni, ks) dst = *(const bf16x8*)(smem + 65536 + jdb * 32768 + \
        (wn * 64 + (ni) * 16 + (lane & 15)) * 128 + \
        ((((ks) * 64) + ((lane >> 4) << 4)) ^ ((lane & 7) << 4)))
#define MFMA_HALF(FI0, AR) do { \
        __builtin_amdgcn_s_setprio(1); \
        _Pragma("unroll") \
        for (int mi = 0; mi < 2; ++mi) \
            _Pragma("unroll") \
            for (int ni = 0; ni < 4; ++ni) \
                _Pragma("unroll") \
                for (int ks = 0; ks < 2; ++ks) \
                    acc[(FI0) + mi][ni] = __builtin_amdgcn_mfma_f32_16x16x32_bf16( \
                        AR[mi][ks], bF[ni][ks], acc[(FI0) + mi][ni], 0, 0, 0); \
        __builtin_amdgcn_s_setprio(0); \
    } while (0)

// Generate B-half hh of tile Tn into its swizzled LDS slots; value/layout
// bit-identical to what the attT gload path staged.
#define GEN_HALF(Tn, hh) do { \
        int kidx = (Tn) * 64 + (((lane & 7) ^ (lane >> 3)) << 3); \
        float4 g0 = *(const float4*)&qzs[kidx]; \
        float4 g1 = *(const float4*)&qzs[kidx + 2]; \
        float4 g2 = *(const float4*)&qzs[kidx + 4]; \
        float4 g3 = *(const float4*)&qzs[kidx + 6]; \
        _Pragma("unroll") \
        for (int i = 0; i < 2; ++i) { \
            float kk = kvr[(hh) * 2 + i]; \
            union { u32 u[4]; bf16x8 v; } pk; \
            pk.u[0] = (u32)f2bf(__expf(g0.x * kk) * g0.y) | ((u32)f2bf(__expf(g0.z * kk) * g0.w) << 16); \
            pk.u[1] = (u32)f2bf(__expf(g1.x * kk) * g1.y) | ((u32)f2bf(__expf(g1.z * kk) * g1.w) << 16); \
            pk.u[2] = (u32)f2bf(__expf(g2.x * kk) * g2.y) | ((u32)f2bf(__expf(g2.z * kk) * g2.w) << 16); \
            pk.u[3] = (u32)f2bf(__expf(g3.x * kk) * g3.y) | ((u32)f2bf(__expf(g3.z * kk) * g3.w) << 16); \
            *(bf16x8*)(smem + 65536 + ((Tn) & 1) * 32768 + (hh) * 16384 + \
                       (i * 8 + w) * 1024 + lane * 16) = pk.v; \
        } \
    } while (0)

    // Prologue: qz -> LDS (PER-LANE source: wave w, lane l loads bytes
    // [w*1024 + l*16, +16) of the 8 KB qz table), A halves t0+A0(t1), gen B(t0).
    {
        const char* qsrc = (const char*)(qzg + (size_t)b * N) + w * 1024 + lane * 16;
        __builtin_amdgcn_global_load_lds(
            (const __attribute__((address_space(1))) u32*)qsrc,
            (__attribute__((address_space(3))) u32*)(smem + 131072 + w * 1024), 16, 0, 0);
    }
    stageA2(Aptr, m0b, smem, 0, 0, w, lane);
    stageA2(Aptr, m0b, smem, 0, 1, w, lane);
    stageA2(Aptr, m0b, smem, 1, 0, w, lane);
    asm volatile("s_waitcnt vmcnt(6)" ::: "memory");   // 7 issued -> qz landed
    __builtin_amdgcn_s_barrier();                      // qzs visible to all
    GEN_HALF(0, 0);
    GEN_HALF(0, 1);
    asm volatile("s_waitcnt lgkmcnt(0)" ::: "memory"); // my B(t0) writes done
    asm volatile("s_waitcnt vmcnt(2)" ::: "memory");   // A(t0) landed
    __builtin_amdgcn_s_barrier();
    __builtin_amdgcn_sched_barrier(0);

    #pragma unroll 1
    for (int j = 0; j < 16; ++j) {
        const int jdb = j & 1;
        // p1: all B frags + A frags 0-3; stage A1(t+1) [other parity]
        LDA_(aP[0][0], 0, 0); LDA_(aP[0][1], 0, 1);
        LDA_(aP[1][0], 1, 0); LDA_(aP[1][1], 1, 1);
        LDA_(aQ[0][0], 2, 0); LDA_(aQ[0][1], 2, 1);
        LDA_(aQ[1][0], 3, 0); LDA_(aQ[1][1], 3, 1);
        LDB_(bF[0][0], 0, 0); LDB_(bF[0][1], 0, 1);
        LDB_(bF[1][0], 1, 0); LDB_(bF[1][1], 1, 1);
        LDB_(bF[2][0], 2, 0); LDB_(bF[2][1], 2, 1);
        LDB_(bF[3][0], 3, 0); LDB_(bF[3][1], 3, 1);
        if (j < 15) stageA2(Aptr, m0b, smem, j + 1, 1, w, lane);
        __builtin_amdgcn_s_barrier();
        asm volatile("s_waitcnt lgkmcnt(0)" ::: "memory");
        MFMA_HALF(0, aP);
        __builtin_amdgcn_s_barrier();
        // p2: A frags 4-5; gen B0(t+1) post-MFMA [opposite parity]
        LDA_(aP[0][0], 4, 0); LDA_(aP[0][1], 4, 1);
        LDA_(aP[1][0], 5, 0); LDA_(aP[1][1], 5, 1);
        __builtin_amdgcn_s_barrier();
        asm volatile("s_waitcnt lgkmcnt(0)" ::: "memory");
        MFMA_HALF(2, aQ);
        if (j < 15) GEN_HALF(j + 1, 0);
        __builtin_amdgcn_s_barrier();
        // p3: A frags 6-7; gen B1(t+1) post-MFMA
        LDA_(aQ[0][0], 6, 0); LDA_(aQ[0][1], 6, 1);
        LDA_(aQ[1][0], 7, 0); LDA_(aQ[1][1], 7, 1);
        __builtin_amdgcn_s_barrier();
        asm volatile("s_waitcnt lgkmcnt(0)" ::: "memory");
        MFMA_HALF(4, aP);
        if (j < 15) GEN_HALF(j + 1, 1);
        __builtin_amdgcn_s_barrier();
        // p4: stage A0(t+2) [same parity; A reads done by p3]
        if (j < 14) stageA2(Aptr, m0b, smem, j + 2, 0, w, lane);
        __builtin_amdgcn_s_barrier();
        asm volatile("s_waitcnt lgkmcnt(0)" ::: "memory");
        MFMA_HALF(6, aQ);
        if (j < 14)       asm volatile("s_waitcnt vmcnt(2)" ::: "memory");
        else if (j == 14) asm volatile("s_waitcnt vmcnt(0)" ::: "memory");
        __builtin_amdgcn_s_barrier();
        __builtin_amdgcn_sched_barrier(0);
    }
#undef LDA_
#undef LDB_
#undef MFMA_HALF
#undef GEN_HALF

    int r4 = (lane >> 4) * 4, cc = lane & 15;
    float* Cb = C + (size_t)b * 1024 * 1024;
    #pragma unroll
    for (int fi = 0; fi < 8; ++fi)
        #pragma unroll
        for (int ni = 0; ni < 4; ++ni)
            #pragma unroll
            for (int rg = 0; rg < 4; ++rg) {
                int row = m0b + wm * 128 + fi * 16 + r4 + rg;
                int col = n0b + wn * 64 + ni * 16 + cc;
                Cb[(size_t)row * 1024 + col] = acc[fi][ni][rg];
            }
}

// ---------------------------------------------------------------------------
extern "C" void kernel_launch(void* const* d_in, const int* in_sizes, int n_in,
                              void* d_out, int out_size, void* d_ws, size_t ws_size,
                              hipStream_t stream)
{
    const float* x  = (const float*)d_in[0];
    const float* Wq = (const float*)d_in[1];
    const float* bq = (const float*)d_in[2];
    const float* Wk = (const float*)d_in[3];
    const float* bk = (const float*)d_in[4];
    const float* Wv = (const float*)d_in[5];
    const float* bv = (const float*)d_in[6];

    float* out = (float*)d_out;                 // (bs, n, d) raw-reshape of (bs, d, n)
    float* att = out + (size_t)BS * N * N;      // (bs, n, n)

    char* ws = (char*)d_ws;
    u16*  xb   = (u16*)ws;                         // BS*N*DIM bf16
    u16*  vb   = xb + (size_t)BS * N * DIM;        // BS*DIM*N bf16
    u16*  Wvb  = vb + (size_t)BS * N * DIM;        // DIM*DIM bf16
    float* qv  = (float*)(Wvb + (size_t)DIM * DIM);
    float* kv  = qv + BS * N;
    float2* qzg = (float2*)(kv + BS * N);          // BS*N float2

    convert_qk<<<(BS * N + DIM) / 4, 256, 0, stream>>>(x, Wq, bq, Wk, bk, Wv, xb, Wvb, qv, kv);
    qz_writer<<<BS * 64, 256, 0, stream>>>(qv, kv, qzg);
    gemm8p<<<512, 512, 0, stream>>>(Wvb, 0, xb, (size_t)N * DIM, vb, (size_t)N * DIM, bv);
    gemm2f<<<512, 512, 0, stream>>>(vb, qzg, kv, out);
    att_tiles<<<BS * 256, 256, 0, stream>>>(qzg, kv, att);
}

// Round 5
// 523.924 us; speedup vs baseline: 1.0264x; 1.0264x over previous
//
#include <hip/hip_runtime.h>
#include <hip/hip_bf16.h>

// Problem constants
#define BS  32
#define N   1024
#define DIM 1024

typedef unsigned short u16;
typedef unsigned int   u32;

typedef __attribute__((ext_vector_type(8))) __bf16 bf16x8;
typedef __attribute__((ext_vector_type(4))) float  f32x4;

__device__ __forceinline__ u16 f2bf(float f) {
    u32 u = __builtin_bit_cast(u32, f);
    u = (u + 0x7FFF + ((u >> 16) & 1)) >> 16;   // RNE, finite inputs only
    return (u16)u;
}

// ---------------------------------------------------------------------------
// K1: convert x (and Wv) to bf16, fused with q = x.Wq+bq, k = x.Wk+bk.
__global__ void convert_qk(const float* __restrict__ x,
                           const float* __restrict__ Wq, const float* __restrict__ bq,
                           const float* __restrict__ Wk, const float* __restrict__ bk,
                           const float* __restrict__ Wv,
                           u16* __restrict__ xb, u16* __restrict__ Wvb,
                           float* __restrict__ qv, float* __restrict__ kv)
{
    int gw   = (blockIdx.x * 256 + threadIdx.x) >> 6;
    int lane = threadIdx.x & 63;
    bool isX = gw < BS * N;
    const float* src = isX ? (x + (size_t)gw * DIM) : (Wv + (size_t)(gw - BS * N) * DIM);
    u16*         dst = isX ? (xb + (size_t)gw * DIM) : (Wvb + (size_t)(gw - BS * N) * DIM);
    float qd = 0.f, kd = 0.f;
    #pragma unroll
    for (int i = 0; i < 4; ++i) {
        int e = i * 256 + lane * 4;
        float4 xv = *(const float4*)&src[e];
        uint2 p;
        p.x = (u32)f2bf(xv.x) | ((u32)f2bf(xv.y) << 16);
        p.y = (u32)f2bf(xv.z) | ((u32)f2bf(xv.w) << 16);
        *(uint2*)&dst[e] = p;
        if (isX) {
            float4 wq = *(const float4*)&Wq[e];
            float4 wk = *(const float4*)&Wk[e];
            qd += xv.x * wq.x + xv.y * wq.y + xv.z * wq.z + xv.w * wq.w;
            kd += xv.x * wk.x + xv.y * wk.y + xv.z * wk.z + xv.w * wk.w;
        }
    }
    if (isX) {
        #pragma unroll
        for (int off = 32; off; off >>= 1) {
            qd += __shfl_xor(qd, off);
            kd += __shfl_xor(kd, off);
        }
        if (lane == 0) { qv[gw] = qd + bq[0]; kv[gw] = kd + bk[0]; }
    }
}

// ---------------------------------------------------------------------------
// K2: Z row-sums only -> (q, invZ) pairs.
__global__ void qz_writer(const float* __restrict__ qv, const float* __restrict__ kvg,
                          float2* __restrict__ qzg)
{
    int blk = blockIdx.x;
    int b   = blk >> 6;
    int r0  = (blk & 63) * 16;
    __shared__ float ks[1024];
    int tid = threadIdx.x;
    #pragma unroll
    for (int i = 0; i < 4; ++i) ks[i * 256 + tid] = kvg[b * N + i * 256 + tid];
    int row = tid >> 4;
    int c16 = tid & 15;
    float qrow = qv[b * N + r0 + row];
    __syncthreads();
    float z = 0.f;
    #pragma unroll 4
    for (int s = 0; s < 16; ++s) {
        const float4 kk = *(const float4*)&ks[(c16 + s * 16) * 4];
        z += __expf(qrow * kk.x) + __expf(qrow * kk.y)
           + __expf(qrow * kk.z) + __expf(qrow * kk.w);
    }
    z += __shfl_xor(z, 1); z += __shfl_xor(z, 2);
    z += __shfl_xor(z, 4); z += __shfl_xor(z, 8);
    if (c16 == 0) qzg[b * N + r0 + row] = make_float2(qrow, 1.0f / z);
}

// ---------------------------------------------------------------------------
// K2b: 64x64 tiles of attention. exp computed once; writes fp32 att and
// bf16 att^T (GEMM2 operand), both coalesced. attT is L3-resident (67 MB)
// so gemm2's B-read mostly never touches HBM — keeping B-gen off the GEMM
// critical path (round-4 lesson: in-loop GEN costs more than this round-trip).
__global__ void att_tiles(const float2* __restrict__ qzg, const float* __restrict__ kvg,
                          float* __restrict__ att, u16* __restrict__ attT)
{
    int blk  = blockIdx.x;
    int b    = blk >> 8;
    int rest = blk & 255;
    int r0 = (rest >> 4) * 64;
    int c0 = (rest & 15) * 64;
    int tid = threadIdx.x;
    int tx = tid & 15, ty = tid >> 4;

    float q[4], iz[4];
    #pragma unroll
    for (int i = 0; i < 4; ++i) {
        float2 p = qzg[(size_t)b * N + r0 + tx * 4 + i];
        q[i] = p.x; iz[i] = p.y;
    }
    float kvj[4];
    #pragma unroll
    for (int j = 0; j < 4; ++j) kvj[j] = kvg[(size_t)b * N + c0 + ty * 4 + j];

    float e[4][4];
    #pragma unroll
    for (int i = 0; i < 4; ++i)
        #pragma unroll
        for (int j = 0; j < 4; ++j)
            e[i][j] = __expf(q[i] * kvj[j]) * iz[i];

    float* ab = att + (size_t)b * N * N;
    #pragma unroll
    for (int i = 0; i < 4; ++i) {
        float4 o = make_float4(e[i][0], e[i][1], e[i][2], e[i][3]);
        *(float4*)&ab[(size_t)(r0 + tx * 4 + i) * N + c0 + ty * 4] = o;
    }
    u16* tb = attT + (size_t)b * N * N;
    #pragma unroll
    for (int j = 0; j < 4; ++j) {
        uint2 p;
        p.x = (u32)f2bf(e[0][j]) | ((u32)f2bf(e[1][j]) << 16);
        p.y = (u32)f2bf(e[2][j]) | ((u32)f2bf(e[3][j]) << 16);
        *(uint2*)&tb[(size_t)(c0 + ty * 4 + j) * N + r0 + tx * 4] = p;
    }
}

// ===========================================================================
// 8-phase 256x256 GEMM (T2+T3+T4+T5), C[b] = A[b] (1024xK rm) @ B[b]^T (1024xK rm).
// 512 thr = 8 waves (2M x 4N); BK=64; LDS 128 KiB (2 dbuf x 32 KiB x {A,B}).
// Swizzle: byte ^= ((row&7)<<4) — involution; applied to pre-swizzled global
// source (linear global_load_lds dest) and to ds_read addresses.
// Half-stage order per tile t: B0,B1,A0,A1 (ids 0..3). Prologue stages halves
// 0..6; tile j phases 1..4 stage halves 7+4j..10+4j; vmcnt(6) per tile
// (=3 half-tiles x 2 loads in flight), vmcnt(0) at tile 14.
// Race-freedom (barrier-ordered): all B-frags read in phase 1; A-frags done by
// phase 3 => same-buffer stages at phases 2 (B0), 3 (B1), 4 (A0) issue strictly
// after the last read of the rows they overwrite; A1(t+2) issues next tile p1.
// ===========================================================================

__device__ __forceinline__ void stage_half8(const u16* __restrict__ Aptr,
                                            const u16* __restrict__ Bptr,
                                            int m0b, int n0b, char* smem,
                                            int h, int w, int lane)
{
    if (h >= 64) return;
    int tile = h >> 2, id = h & 3;
    int db   = tile & 1;
    const u16* G = (id < 2) ? Bptr : Aptr;
    int opb   = (id < 2) ? 65536 : 0;
    int row0  = (id < 2) ? n0b : m0b;
    int halfb = (id & 1) * 16384;
    int kb    = tile * 128;                       // BK=64 -> 128 bytes
    int cb    = ((lane & 7) ^ (lane >> 3)) << 4;  // pre-swizzled source column
    #pragma unroll
    for (int i = 0; i < 2; ++i) {
        int lofs = opb + db * 32768 + halfb + (i * 8 + w) * 1024;  // wave-uniform
        int r    = (id & 1) * 128 + (i * 8 + w) * 8 + (lane >> 3);
        const char* src = (const char*)G + (size_t)(row0 + r) * 2048 + kb + cb;
        __builtin_amdgcn_global_load_lds(
            (const __attribute__((address_space(1))) u32*)src,
            (__attribute__((address_space(3))) u32*)(smem + lofs), 16, 0, 0);
    }
}

template<bool BF16OUT>
__global__ __launch_bounds__(512, 2) void gemm8p(
    const u16* __restrict__ A, size_t aBatch,
    const u16* __restrict__ B, size_t bBatch,
    void* __restrict__ Cv, size_t cBatch,
    const float* __restrict__ bias)
{
    __shared__ char smem[131072];
    // XCD-aware swizzle: 512 blocks, 64 contiguous per XCD (4 whole batches).
    int bid = blockIdx.x;
    int lin = (bid & 7) * 64 + (bid >> 3);
    int b   = lin >> 4;
    int t16 = lin & 15;
    int m0b = (t16 >> 2) * 256, n0b = (t16 & 3) * 256;
    const u16* Aptr = A + aBatch * (size_t)b;
    const u16* Bptr = B + bBatch * (size_t)b;

    int tid  = threadIdx.x;
    int w    = tid >> 6, lane = tid & 63;
    int wm   = w >> 2, wn = w & 3;          // 2 x 4 wave grid; wave tile 128x64

    f32x4 acc[8][4] = {};
    bf16x8 aP[2][2], aQ[2][2], bF[4][2];

    // Reads (swizzled): frag rows have row&7 == lane&7 (all row bases %8==0).
#define LDA_(dst, fi, ks) dst = *(const bf16x8*)(smem + jdb * 32768 + \
        (wm * 128 + (fi) * 16 + (lane & 15)) * 128 + \
        ((((ks) * 64) + ((lane >> 4) << 4)) ^ ((lane & 7) << 4)))
#define LDB_(dst, ni, ks) dst = *(const bf16x8*)(smem + 65536 + jdb * 32768 + \
        (wn * 64 + (ni) * 16 + (lane & 15)) * 128 + \
        ((((ks) * 64) + ((lane >> 4) << 4)) ^ ((lane & 7) << 4)))
#define MFMA_HALF(FI0, AR) do { \
        __builtin_amdgcn_s_setprio(1); \
        _Pragma("unroll") \
        for (int mi = 0; mi < 2; ++mi) \
            _Pragma("unroll") \
            for (int ni = 0; ni < 4; ++ni) \
                _Pragma("unroll") \
                for (int ks = 0; ks < 2; ++ks) \
                    acc[(FI0) + mi][ni] = __builtin_amdgcn_mfma_f32_16x16x32_bf16( \
                        AR[mi][ks], bF[ni][ks], acc[(FI0) + mi][ni], 0, 0, 0); \
        __builtin_amdgcn_s_setprio(0); \
    } while (0)

    // Prologue: halves 0..6 (tile0 complete + B0,B1,A0 of tile1); wait tile0.
    #pragma unroll
    for (int h = 0; h < 7; ++h) stage_half8(Aptr, Bptr, m0b, n0b, smem, h, w, lane);
    asm volatile("s_waitcnt vmcnt(6)" ::: "memory");   // 14 issued -> halves 0..3 landed
    __builtin_amdgcn_s_barrier();
    __builtin_amdgcn_sched_barrier(0);

    #pragma unroll 1
    for (int j = 0; j < 16; ++j) {
        const int jdb = j & 1;
        // ---- phase 1: all B frags + A frags 0-3; stage A1(t_{j+1}) [other buf]
        LDA_(aP[0][0], 0, 0); LDA_(aP[0][1], 0, 1);
        LDA_(aP[1][0], 1, 0); LDA_(aP[1][1], 1, 1);
        LDA_(aQ[0][0], 2, 0); LDA_(aQ[0][1], 2, 1);
        LDA_(aQ[1][0], 3, 0); LDA_(aQ[1][1], 3, 1);
        LDB_(bF[0][0], 0, 0); LDB_(bF[0][1], 0, 1);
        LDB_(bF[1][0], 1, 0); LDB_(bF[1][1], 1, 1);
        LDB_(bF[2][0], 2, 0); LDB_(bF[2][1], 2, 1);
        LDB_(bF[3][0], 3, 0); LDB_(bF[3][1], 3, 1);
        stage_half8(Aptr, Bptr, m0b, n0b, smem, 7 + 4 * j, w, lane);
        __builtin_amdgcn_s_barrier();
        asm volatile("s_waitcnt lgkmcnt(0)" ::: "memory");
        MFMA_HALF(0, aP);
        __builtin_amdgcn_s_barrier();
        // ---- phase 2: A frags 4-5; stage B0(t_{j+2}) [B reads done p1]
        LDA_(aP[0][0], 4, 0); LDA_(aP[0][1], 4, 1);
        LDA_(aP[1][0], 5, 0); LDA_(aP[1][1], 5, 1);
        stage_half8(Aptr, Bptr, m0b, n0b, smem, 8 + 4 * j, w, lane);
        __builtin_amdgcn_s_barrier();
        asm volatile("s_waitcnt lgkmcnt(0)" ::: "memory");
        MFMA_HALF(2, aQ);
        __builtin_amdgcn_s_barrier();
        // ---- phase 3: A frags 6-7; stage B1(t_{j+2}) [B reads done p1]
        LDA_(aQ[0][0], 6, 0); LDA_(aQ[0][1], 6, 1);
        LDA_(aQ[1][0], 7, 0); LDA_(aQ[1][1], 7, 1);
        stage_half8(Aptr, Bptr, m0b, n0b, smem, 9 + 4 * j, w, lane);
        __builtin_amdgcn_s_barrier();
        asm volatile("s_waitcnt lgkmcnt(0)" ::: "memory");
        MFMA_HALF(4, aP);
        __builtin_amdgcn_s_barrier();
        // ---- phase 4: stage A0(t_{j+2}) [A reads done p3]; vmcnt; tile done
        stage_half8(Aptr, Bptr, m0b, n0b, smem, 10 + 4 * j, w, lane);
        __builtin_amdgcn_s_barrier();
        asm volatile("s_waitcnt lgkmcnt(0)" ::: "memory");
        MFMA_HALF(6, aQ);
        if (j < 14)       asm volatile("s_waitcnt vmcnt(6)" ::: "memory");
        else if (j == 14) asm volatile("s_waitcnt vmcnt(0)" ::: "memory");
        __builtin_amdgcn_s_barrier();
        __builtin_amdgcn_sched_barrier(0);
    }
#undef LDA_
#undef LDB_
#undef MFMA_HALF

    // Epilogue: C/D map col=lane&15, row=(lane>>4)*4+rg.
    int r4 = (lane >> 4) * 4, cc = lane & 15;
    if constexpr (BF16OUT) {
        u16* Cb = (u16*)Cv + cBatch * (size_t)b;
        #pragma unroll
        for (int fi = 0; fi < 8; ++fi)
            #pragma unroll
            for (int ni = 0; ni < 4; ++ni)
                #pragma unroll
                for (int rg = 0; rg < 4; ++rg) {
                    int row = m0b + wm * 128 + fi * 16 + r4 + rg;
                    int col = n0b + wn * 64 + ni * 16 + cc;
                    Cb[(size_t)row * 1024 + col] = f2bf(acc[fi][ni][rg] + bias[row]);
                }
    } else {
        float* Cb = (float*)Cv + cBatch * (size_t)b;
        #pragma unroll
        for (int fi = 0; fi < 8; ++fi)
            #pragma unroll
            for (int ni = 0; ni < 4; ++ni)
                #pragma unroll
                for (int rg = 0; rg < 4; ++rg) {
                    int row = m0b + wm * 128 + fi * 16 + r4 + rg;
                    int col = n0b + wn * 64 + ni * 16 + cc;
                    Cb[(size_t)row * 1024 + col] = acc[fi][ni][rg];
                }
    }
}

// ---------------------------------------------------------------------------
extern "C" void kernel_launch(void* const* d_in, const int* in_sizes, int n_in,
                              void* d_out, int out_size, void* d_ws, size_t ws_size,
                              hipStream_t stream)
{
    const float* x  = (const float*)d_in[0];
    const float* Wq = (const float*)d_in[1];
    const float* bq = (const float*)d_in[2];
    const float* Wk = (const float*)d_in[3];
    const float* bk = (const float*)d_in[4];
    const float* Wv = (const float*)d_in[5];
    const float* bv = (const float*)d_in[6];

    float* out = (float*)d_out;                 // (bs, n, d) raw-reshape of (bs, d, n)
    float* att = out + (size_t)BS * N * N;      // (bs, n, n)

    char* ws = (char*)d_ws;
    u16*  xb   = (u16*)ws;                         // BS*N*DIM bf16
    u16*  vb   = xb + (size_t)BS * N * DIM;        // BS*DIM*N bf16
    u16*  Wvb  = vb + (size_t)BS * N * DIM;        // DIM*DIM bf16
    float* qv  = (float*)(Wvb + (size_t)DIM * DIM);
    float* kv  = qv + BS * N;
    float2* qzg = (float2*)(kv + BS * N);          // BS*N float2
    u16*  attT = (u16*)(qzg + BS * N);             // BS*N*N bf16

    convert_qk<<<(BS * N + DIM) / 4, 256, 0, stream>>>(x, Wq, bq, Wk, bk, Wv, xb, Wvb, qv, kv);
    qz_writer<<<BS * 64, 256, 0, stream>>>(qv, kv, qzg);
    gemm8p<true><<<512, 512, 0, stream>>>(Wvb, 0, xb, (size_t)N * DIM, vb, (size_t)N * DIM, bv);
    att_tiles<<<BS * 256, 256, 0, stream>>>(qzg, kv, att, attT);
    gemm8p<false><<<512, 512, 0, stream>>>(vb, (size_t)N * DIM, attT, (size_t)N * N, out, (size_t)N * DIM, nullptr);
}